// Round 2
// baseline (154.745 us; speedup 1.0000x reference)
//
#include <hip/hip_runtime.h>

// x:  [N=4, C=256, H=56, W=56] fp32
// w1: [N, 1, 32, 9,  H, W]     (3x3, pad 1)
// w2: [N, 1, 32, 25, H, W]     (5x5, pad 2)
// out:[N, 2, 1, C, H, W]
// out[n,b,c,h,w] = sum_p wB[n, c%32, p, h, w] * x[n, c, h+dh, w+dw] (zero pad)
//
// R10: LDS staging REMOVED. Evidence: R8 (~151 MB nominal traffic) and R9
// (~100 MB) timed identical (113.2 vs 115.2 us) => kernel is NOT BW-bound;
// the staging barrier + 196/256 active lanes + 1024-block lockstep were the
// limiter. New shape: 1 thread = (n, c, h, 8-col seg), both branches.
//  - 1568 blocks x 256 threads, every lane computes, no barrier, no LDS.
//  - weights (54.6 MB, read once) keep the proven cur/nxt 1-row-ahead
//    prefetch; x rows loaded per-di directly (x is 12.8 MB total, 5x re-read
//    is L1/L2/L3-served; wave access pattern is ~2 KB contiguous per instr).
//  - col halo via predicated float2 loads (8B-aligned since wb is even);
//    row halo via xr bounds check (zero window).

#define N_  4
#define C_  256
#define H_  56
#define W_  56
#define HW_ 3136
#define WC_ 32

__global__ __launch_bounds__(256) void lconv_kernel(
    const float* __restrict__ x,
    const float* __restrict__ w1,
    const float* __restrict__ w2,
    float* __restrict__ out)
{
    const int gid  = blockIdx.x * 256 + threadIdx.x;
    const int wseg = gid % 7;            // 7 segments of 8 cols
    int t = gid / 7;
    const int h = t % H_;
    t /= H_;
    const int c = t & (C_ - 1);
    const int n = t >> 8;
    const int v = c & (WC_ - 1);
    const int wb = wseg * 8;
    const int hw = h * W_ + wb;

    const float* xpl = x + (size_t)(n * C_ + c) * HW_;
    const float* w2t = w2 + (size_t)(n * WC_ + v) * 25 * HW_ + hw;
    const float* w1t = w1 + (size_t)(n * WC_ + v) * 9  * HW_ + hw;

    // ================= 5x5 branch: pipelined w2 stream =================
    float a2[8];
    #pragma unroll
    for (int p = 0; p < 8; ++p) a2[p] = 0.f;

    float4 wcur[10], wnxt[10];
    #pragma unroll
    for (int dj = 0; dj < 5; ++dj) {
        wcur[2*dj]   = *(const float4*)(w2t + (size_t)dj * HW_);
        wcur[2*dj+1] = *(const float4*)(w2t + (size_t)dj * HW_ + 4);
    }

    #pragma unroll 1
    for (int di = 0; di < 5; ++di) {
        if (di < 4) {
            #pragma unroll
            for (int dj = 0; dj < 5; ++dj) {
                wnxt[2*dj]   = *(const float4*)(w2t + (size_t)((di+1)*5 + dj) * HW_);
                wnxt[2*dj+1] = *(const float4*)(w2t + (size_t)((di+1)*5 + dj) * HW_ + 4);
            }
        }
        // x window: cols wb-2 .. wb+9 of row h-2+di (zero padded)
        float xw[12];
        const int xr = h - 2 + di;
        if (xr >= 0 && xr < H_) {
            const float* xp = xpl + xr * W_ + wb;
            const float4 xb4 = *(const float4*)(xp);
            const float4 xc4 = *(const float4*)(xp + 4);
            float2 xa2 = make_float2(0.f, 0.f);
            float2 xd2 = make_float2(0.f, 0.f);
            if (wseg > 0) xa2 = *(const float2*)(xp - 2);
            if (wseg < 6) xd2 = *(const float2*)(xp + 8);
            xw[0]  = xa2.x; xw[1]  = xa2.y;
            xw[2]  = xb4.x; xw[3]  = xb4.y; xw[4] = xb4.z; xw[5] = xb4.w;
            xw[6]  = xc4.x; xw[7]  = xc4.y; xw[8] = xc4.z; xw[9] = xc4.w;
            xw[10] = xd2.x; xw[11] = xd2.y;
        } else {
            #pragma unroll
            for (int q = 0; q < 12; ++q) xw[q] = 0.f;
        }
        #pragma unroll
        for (int dj = 0; dj < 5; ++dj) {
            const float* wlo = (const float*)&wcur[2*dj];
            const float* whi = (const float*)&wcur[2*dj+1];
            #pragma unroll
            for (int p = 0; p < 4; ++p) {
                a2[p]     += wlo[p] * xw[p + dj];       // out col wb+p
                a2[p + 4] += whi[p] * xw[p + 4 + dj];   // out col wb+4+p
            }
        }
        if (di < 4) {
            #pragma unroll
            for (int q = 0; q < 10; ++q) wcur[q] = wnxt[q];
        }
    }

    float* o2 = out + ((size_t)(n * 2 + 1) * C_ + c) * HW_ + hw;
    *(float4*)(o2)     = make_float4(a2[0], a2[1], a2[2], a2[3]);
    *(float4*)(o2 + 4) = make_float4(a2[4], a2[5], a2[6], a2[7]);

    // ================= 3x3 branch: pipelined w1 stream =================
    float a1[8];
    #pragma unroll
    for (int p = 0; p < 8; ++p) a1[p] = 0.f;

    float4 vcur[6], vnxt[6];
    #pragma unroll
    for (int dj = 0; dj < 3; ++dj) {
        vcur[2*dj]   = *(const float4*)(w1t + (size_t)dj * HW_);
        vcur[2*dj+1] = *(const float4*)(w1t + (size_t)dj * HW_ + 4);
    }

    #pragma unroll 1
    for (int di = 0; di < 3; ++di) {
        if (di < 2) {
            #pragma unroll
            for (int dj = 0; dj < 3; ++dj) {
                vnxt[2*dj]   = *(const float4*)(w1t + (size_t)((di+1)*3 + dj) * HW_);
                vnxt[2*dj+1] = *(const float4*)(w1t + (size_t)((di+1)*3 + dj) * HW_ + 4);
            }
        }
        // x window: cols wb-2 .. wb+9 of row h-1+di (only xw[1..10] used)
        float xw[12];
        const int xr = h - 1 + di;
        if (xr >= 0 && xr < H_) {
            const float* xp = xpl + xr * W_ + wb;
            const float4 xb4 = *(const float4*)(xp);
            const float4 xc4 = *(const float4*)(xp + 4);
            float2 xa2 = make_float2(0.f, 0.f);
            float2 xd2 = make_float2(0.f, 0.f);
            if (wseg > 0) xa2 = *(const float2*)(xp - 2);
            if (wseg < 6) xd2 = *(const float2*)(xp + 8);
            xw[0]  = xa2.x; xw[1]  = xa2.y;
            xw[2]  = xb4.x; xw[3]  = xb4.y; xw[4] = xb4.z; xw[5] = xb4.w;
            xw[6]  = xc4.x; xw[7]  = xc4.y; xw[8] = xc4.z; xw[9] = xc4.w;
            xw[10] = xd2.x; xw[11] = xd2.y;
        } else {
            #pragma unroll
            for (int q = 0; q < 12; ++q) xw[q] = 0.f;
        }
        #pragma unroll
        for (int dj = 0; dj < 3; ++dj) {
            const float* wlo = (const float*)&vcur[2*dj];
            const float* whi = (const float*)&vcur[2*dj+1];
            #pragma unroll
            for (int p = 0; p < 4; ++p) {
                a1[p]     += wlo[p] * xw[p + dj + 1];     // out col wb+p
                a1[p + 4] += whi[p] * xw[p + dj + 5];     // out col wb+4+p
            }
        }
        if (di < 2) {
            #pragma unroll
            for (int q = 0; q < 6; ++q) vcur[q] = vnxt[q];
        }
    }

    float* o1 = out + ((size_t)(n * 2 + 0) * C_ + c) * HW_ + hw;
    *(float4*)(o1)     = make_float4(a1[0], a1[1], a1[2], a1[3]);
    *(float4*)(o1 + 4) = make_float4(a1[4], a1[5], a1[6], a1[7]);
}

extern "C" void kernel_launch(void* const* d_in, const int* in_sizes, int n_in,
                              void* d_out, int out_size, void* d_ws, size_t ws_size,
                              hipStream_t stream) {
    const float* x  = (const float*)d_in[0];
    const float* w1 = (const float*)d_in[1];
    const float* w2 = (const float*)d_in[2];
    float* out = (float*)d_out;

    // 4*256*56*7 = 401408 threads = exactly 1568 blocks of 256
    dim3 grid(1568), block(256);
    hipLaunchKernelGGL(lconv_kernel, grid, block, 0, stream, x, w1, w2, out);
}

// Round 3
// 119.870 us; speedup vs baseline: 1.2909x; 1.2909x over previous
//
#include <hip/hip_runtime.h>

// x:  [N=4, C=256, H=56, W=56] fp32
// w1: [N, 1, 32, 9,  H, W]     (3x3, pad 1)
// w2: [N, 1, 32, 25, H, W]     (5x5, pad 2)
// out:[N, 2, 1, C, H, W]
// out[n,b,c,h,w] = sum_p wB[n, c%32, p, h, w] * x[n, c, h+dh, w+dw] (zero pad)
//
// R11 = R9 block structure (one block = (n, v, row-tile), weights fetched
// once from HBM; R10 proved scattering c across blocks duplicates the weight
// stream per-XCD: FETCH 227 MB, 70 us) with the latency fixes R9 lacked:
//  (1) TILE 7->4: grid 1792, LDS 17.4 KB -> ~6-7 blocks/CU co-resident
//      (was 4 lockstep). Other blocks' compute hides each wave's ~900cyc
//      weight-miss stalls and the staging barrier.
//  (2) 3x3 branch MERGED into the 5x5 di-loop (x rows h-1..h+1 are di=1..3
//      of the 5x5 window): one LDS window read feeds both branches, and both
//      weight streams are in flight together (deeper memory pipeline).
//  (3) compute = 224 threads (row 0..3, seg 0..13, gq 0..3), 2 groups/thread
//      {gq, gq+4}: 87.5% lane utilization (was 76.5%).
// LSTRIDE 68 bank stagger kept (R8's proven conflict fix).

#define N_  4
#define C_  256
#define H_  56
#define W_  56
#define HW_ 3136
#define WC_ 32

#define TILE    4
#define LROWS   8    // TILE + 4 halo rows
#define NPL     8    // all 8 channel groups staged
#define LSTRIDE 68   // x col c -> slot c+2; slots 0,1 & 58,59 zero halo

__global__ __launch_bounds__(256) void lconv_kernel(
    const float* __restrict__ x,
    const float* __restrict__ w1,
    const float* __restrict__ w2,
    float* __restrict__ out)
{
    __shared__ float lds[NPL * LROWS * LSTRIDE];   // 17408 B

    const int b    = blockIdx.x;        // 0..1791
    const int v    = b & 31;
    const int n    = (b >> 5) & 3;
    const int tile = b >> 7;            // 0..13; tiles of one (n,v) same XCD
    const int r0   = tile * TILE;
    const int nv   = n * WC_ + v;
    const int tid  = threadIdx.x;

    // ---- stage x: 8 planes x 8 rows x 56 cols; zero OOB rows ----
    for (int idx = tid; idx < NPL * LROWS * 14; idx += 256) {   // 896 float4
        const int c4 = idx % 14;
        const int t2 = idx / 14;
        const int lr = t2 % LROWS;
        const int pl = t2 / LROWS;
        const int gr = r0 - 2 + lr;
        float4 val = make_float4(0.f, 0.f, 0.f, 0.f);
        if (gr >= 0 && gr < H_) {
            const int ch = pl * WC_ + v;
            val = *(const float4*)(x + (size_t)(n * C_ + ch) * HW_ + gr * W_ + c4 * 4);
        }
        float* lp = &lds[(pl * LROWS + lr) * LSTRIDE + 4 * c4 + 2];
        *(float2*)(lp)     = make_float2(val.x, val.y);
        *(float2*)(lp + 2) = make_float2(val.z, val.w);
    }
    // zero column halos: slots 0,1 (x cols -2,-1) and 58,59 (x cols 56,57)
    // 8 planes x 8 rows x 4 slots = 256 -> exactly one per thread
    {
        const int k  = tid & 3;
        const int t2 = tid >> 2;
        const int lr = t2 % LROWS;
        const int pl = t2 / LROWS;
        const int slot = (k < 2) ? k : (56 + k);
        lds[(pl * LROWS + lr) * LSTRIDE + slot] = 0.f;
    }
    __syncthreads();

    if (tid >= 224) return;              // 224 compute threads; no barriers below

    const int gq  = tid / 56;            // 0..3 -> groups {gq, gq+4}
    const int r   = tid - gq * 56;
    const int row = r / 14;              // 0..3
    const int s   = r - row * 14;
    const int wb  = 4 * s;               // 0,4,...,52
    const int h   = r0 + row;
    const int hw  = h * W_ + wb;

    const float* w1t = w1 + (size_t)nv * 9  * HW_ + hw;
    const float* w2t = w2 + (size_t)nv * 25 * HW_ + hw;

    float a2[2][4], a1[2][4];
    #pragma unroll
    for (int gi = 0; gi < 2; ++gi)
        #pragma unroll
        for (int p = 0; p < 4; ++p) { a2[gi][p] = 0.f; a1[gi][p] = 0.f; }

    // ---- merged di-loop: both weight streams pipelined 1 row ahead ----
    float4 w2cur[5], w2nxt[5], w1cur[3], w1nxt[3];
    #pragma unroll
    for (int dj = 0; dj < 5; ++dj)
        w2cur[dj] = *(const float4*)(w2t + (size_t)dj * HW_);
    #pragma unroll
    for (int dj = 0; dj < 3; ++dj)       // w1 row 0, used at di=1
        w1cur[dj] = *(const float4*)(w1t + (size_t)dj * HW_);

    #pragma unroll 1
    for (int di = 0; di < 5; ++di) {
        if (di < 4) {
            #pragma unroll
            for (int dj = 0; dj < 5; ++dj)
                w2nxt[dj] = *(const float4*)(w2t + (size_t)((di + 1) * 5 + dj) * HW_);
        }
        if (di >= 1 && di < 3) {         // prefetch w1 row di, used at di+1
            #pragma unroll
            for (int dj = 0; dj < 3; ++dj)
                w1nxt[dj] = *(const float4*)(w1t + (size_t)(di * 3 + dj) * HW_);
        }
        const int do33 = (di >= 1 && di <= 3);
        #pragma unroll
        for (int gi = 0; gi < 2; ++gi) {
            const int g = gq + gi * 4;
            const float* lp = &lds[(g * LROWS + row + di) * LSTRIDE + wb];
            const float4 xa  = *(const float4*)(lp);
            const float4 xb4 = *(const float4*)(lp + 4);
            const float xw[8] = {xa.x, xa.y, xa.z, xa.w, xb4.x, xb4.y, xb4.z, xb4.w};
            #pragma unroll
            for (int dj = 0; dj < 5; ++dj) {
                const float* wr = (const float*)&w2cur[dj];
                #pragma unroll
                for (int p = 0; p < 4; ++p)
                    a2[gi][p] += wr[p] * xw[p + dj];
            }
            if (do33) {
                #pragma unroll
                for (int dj = 0; dj < 3; ++dj) {
                    const float* wr = (const float*)&w1cur[dj];
                    #pragma unroll
                    for (int p = 0; p < 4; ++p)
                        a1[gi][p] += wr[p] * xw[p + dj + 1];
                }
            }
        }
        if (di < 4) {
            #pragma unroll
            for (int dj = 0; dj < 5; ++dj) w2cur[dj] = w2nxt[dj];
        }
        if (di >= 1 && di < 3) {
            #pragma unroll
            for (int dj = 0; dj < 3; ++dj) w1cur[dj] = w1nxt[dj];
        }
    }

    #pragma unroll
    for (int gi = 0; gi < 2; ++gi) {
        const int ch = (gq + gi * 4) * WC_ + v;
        float* o2 = out + ((size_t)(n * 2 + 1) * C_ + ch) * HW_ + hw;
        float* o1 = out + ((size_t)(n * 2 + 0) * C_ + ch) * HW_ + hw;
        *(float4*)(o2) = make_float4(a2[gi][0], a2[gi][1], a2[gi][2], a2[gi][3]);
        *(float4*)(o1) = make_float4(a1[gi][0], a1[gi][1], a1[gi][2], a1[gi][3]);
    }
}

extern "C" void kernel_launch(void* const* d_in, const int* in_sizes, int n_in,
                              void* d_out, int out_size, void* d_ws, size_t ws_size,
                              hipStream_t stream) {
    const float* x  = (const float*)d_in[0];
    const float* w1 = (const float*)d_in[1];
    const float* w2 = (const float*)d_in[2];
    float* out = (float*)d_out;

    dim3 grid(1792), block(256);   // 4 n x 32 v x 14 tiles
    hipLaunchKernelGGL(lconv_kernel, grid, block, 0, stream, x, w1, w2, out);
}

// Round 4
// 112.267 us; speedup vs baseline: 1.3784x; 1.0677x over previous
//
#include <hip/hip_runtime.h>

// x:  [N=4, C=256, H=56, W=56] fp32
// w1: [N, 1, 32, 9,  H, W]     (3x3, pad 1)
// w2: [N, 1, 32, 25, H, W]     (5x5, pad 2)
// out:[N, 2, 1, C, H, W]
// out[n,b,c,h,w] = sum_p wB[n, c%32, p, h, w] * x[n, c, h+dh, w+dw] (zero pad)
//
// R12 = R8 structure (best measured: TILE 14, gsel split, LSTRIDE 68,
// 196 compute threads, grid 1024 — gsel weight dup is L2-absorbed since the
// pair shares an XCD) + deep weight-load pipelining:
//  - di loops FULLY UNROLLED; w2 rows prefetched 2 ROWS ahead (issue-to-use
//    ~2 iterations ~1500 cyc > 900 cyc HBM latency; R8's depth-1 gave only
//    ~768 cyc with 3 barrier-aligned waves/SIMD -> stalled every row).
//  - all 9 w1 float4 issued once, after w2 rows 0-1: they land during the
//    whole 5x5 phase, so the 3x3 phase starts hot.
//  - full unroll => all weight regs static-indexed (SSA), no scratch.
// Cost: VGPR ~84 -> ~170 (4->3 waves/SIMD) — fine, lookahead is per-wave now.

#define N_  4
#define C_  256
#define H_  56
#define W_  56
#define HW_ 3136
#define WC_ 32

#define TILE    14
#define LROWS   18   // TILE + 4 halo rows
#define LSTRIDE 68   // x col c -> slot c+2; slots 0,1 & 58,59 zero halo

__global__ __launch_bounds__(256) void lconv_kernel(
    const float* __restrict__ x,
    const float* __restrict__ w1,
    const float* __restrict__ w2,
    float* __restrict__ out)
{
    __shared__ float lds[4 * LROWS * LSTRIDE];   // 19584 B

    const int b     = blockIdx.x;        // 0..1023
    const int tile  = b & 3;
    const int vlow  = (b >> 2) & 1;
    const int gsel  = (b >> 3) & 1;      // stride 8 -> gsel-pair on same XCD
    const int vhigh = (b >> 4) & 15;
    const int n     = b >> 8;
    const int v     = (vhigh << 1) | vlow;
    const int r0    = tile * TILE;
    const int nv    = n * WC_ + v;
    const int tid   = threadIdx.x;

    // ---- stage x: 4 planes x 18 rows x 56 cols; zero OOB rows ----
    for (int idx = tid; idx < 4 * LROWS * 14; idx += 256) {
        const int c4 = idx % 14;
        const int t2 = idx / 14;
        const int lr = t2 % LROWS;
        const int pl = t2 / LROWS;
        const int gr = r0 - 2 + lr;
        float4 val = make_float4(0.f, 0.f, 0.f, 0.f);
        if (gr >= 0 && gr < H_) {
            const int ch = gsel * 128 + pl * 32 + v;
            val = *(const float4*)(x + (size_t)(n * C_ + ch) * HW_ + gr * W_ + c4 * 4);
        }
        float* lp = &lds[(pl * LROWS + lr) * LSTRIDE + 4 * c4 + 2];
        *(float2*)(lp)     = make_float2(val.x, val.y);
        *(float2*)(lp + 2) = make_float2(val.z, val.w);
    }
    // zero column halos: slots 0,1 (x cols -2,-1) and 58,59 (x cols 56,57)
    for (int idx = tid; idx < 4 * LROWS * 4; idx += 256) {
        const int k  = idx & 3;
        const int t2 = idx >> 2;
        const int lr = t2 % LROWS;
        const int pl = t2 / LROWS;
        const int slot = (k < 2) ? k : (56 + k);
        lds[(pl * LROWS + lr) * LSTRIDE + slot] = 0.f;
    }
    __syncthreads();

    if (tid >= TILE * 14) return;        // 196 compute threads; no barriers below

    const int row = tid / 14;            // 0..13
    const int s   = tid - row * 14;
    const int wb  = 4 * s;               // 0,4,...,52
    const int h   = r0 + row;
    const int hw  = h * W_ + wb;

    const float* w1t = w1 + (size_t)nv * 9  * HW_ + hw;
    const float* w2t = w2 + (size_t)nv * 25 * HW_ + hw;
    const int c0 = gsel * 128 + v;

    // ================= 5x5 branch: depth-2 row pipeline, full unroll ======
    float a2[4][4];
    #pragma unroll
    for (int g = 0; g < 4; ++g)
        #pragma unroll
        for (int p = 0; p < 4; ++p) a2[g][p] = 0.f;

    float4 w2r[5][5];                    // [di][dj], fully static-indexed
    #pragma unroll
    for (int dj = 0; dj < 5; ++dj)
        w2r[0][dj] = *(const float4*)(w2t + (size_t)dj * HW_);
    #pragma unroll
    for (int dj = 0; dj < 5; ++dj)
        w2r[1][dj] = *(const float4*)(w2t + (size_t)(5 + dj) * HW_);

    // w1 loads issued here: they complete during the whole 5x5 phase
    float4 w1r[9];
    #pragma unroll
    for (int q = 0; q < 9; ++q)
        w1r[q] = *(const float4*)(w1t + (size_t)q * HW_);

    #pragma unroll
    for (int di = 0; di < 5; ++di) {
        if (di + 2 < 5) {                // prefetch row di+2, used 2 iters later
            #pragma unroll
            for (int dj = 0; dj < 5; ++dj)
                w2r[di + 2][dj] = *(const float4*)(w2t + (size_t)((di + 2) * 5 + dj) * HW_);
        }
        #pragma unroll
        for (int g = 0; g < 4; ++g) {
            const float* lp = &lds[(g * LROWS + row + di) * LSTRIDE + wb];
            const float4 xa  = *(const float4*)(lp);
            const float4 xb4 = *(const float4*)(lp + 4);
            const float xw[8] = {xa.x, xa.y, xa.z, xa.w, xb4.x, xb4.y, xb4.z, xb4.w};
            #pragma unroll
            for (int dj = 0; dj < 5; ++dj) {
                const float* wr = (const float*)&w2r[di][dj];
                #pragma unroll
                for (int p = 0; p < 4; ++p)
                    a2[g][p] += wr[p] * xw[p + dj];
            }
        }
    }

    float* o2 = out + ((size_t)(n * 2 + 1) * C_ + c0) * HW_ + hw;
    #pragma unroll
    for (int g = 0; g < 4; ++g)
        *(float4*)(o2 + (size_t)g * WC_ * HW_) =
            make_float4(a2[g][0], a2[g][1], a2[g][2], a2[g][3]);

    // ================= 3x3 branch: weights already in registers ===========
    float a1[4][4];
    #pragma unroll
    for (int g = 0; g < 4; ++g)
        #pragma unroll
        for (int p = 0; p < 4; ++p) a1[g][p] = 0.f;

    #pragma unroll
    for (int di = 0; di < 3; ++di) {
        #pragma unroll
        for (int g = 0; g < 4; ++g) {
            // x rows h-1+di -> LDS row row+1+di
            const float* lp = &lds[(g * LROWS + row + 1 + di) * LSTRIDE + wb];
            const float4 xa  = *(const float4*)(lp);
            const float4 xb4 = *(const float4*)(lp + 4);
            const float xw[8] = {xa.x, xa.y, xa.z, xa.w, xb4.x, xb4.y, xb4.z, xb4.w};
            #pragma unroll
            for (int dj = 0; dj < 3; ++dj) {
                const float* wr = (const float*)&w1r[di * 3 + dj];
                #pragma unroll
                for (int p = 0; p < 4; ++p)
                    a1[g][p] += wr[p] * xw[p + dj + 1];
            }
        }
    }

    float* o1 = out + ((size_t)(n * 2 + 0) * C_ + c0) * HW_ + hw;
    #pragma unroll
    for (int g = 0; g < 4; ++g)
        *(float4*)(o1 + (size_t)g * WC_ * HW_) =
            make_float4(a1[g][0], a1[g][1], a1[g][2], a1[g][3]);
}

extern "C" void kernel_launch(void* const* d_in, const int* in_sizes, int n_in,
                              void* d_out, int out_size, void* d_ws, size_t ws_size,
                              hipStream_t stream) {
    const float* x  = (const float*)d_in[0];
    const float* w1 = (const float*)d_in[1];
    const float* w2 = (const float*)d_in[2];
    float* out = (float*)d_out;

    dim3 grid(1024), block(256);   // 4 blocks/CU
    hipLaunchKernelGGL(lconv_kernel, grid, block, 0, stream, x, w1, w2, out);
}